// Round 11
// baseline (342.584 us; speedup 1.0000x reference)
//
#include <hip/hip_runtime.h>
#include <hip/hip_bf16.h>
#include <stdint.h>

#define RANK 32
#define SCALE (1.0f / 32.0f)

typedef __bf16 bf16x8 __attribute__((ext_vector_type(8)));
typedef float f32x4 __attribute__((ext_vector_type(4)));
typedef float f32x16 __attribute__((ext_vector_type(16)));

// ---------------------------------------------------------------------------
// async global->LDS, 16B per lane
// ---------------------------------------------------------------------------
__device__ __forceinline__ void gload16(const void* g, void* l) {
  __builtin_amdgcn_global_load_lds(
      (const __attribute__((address_space(1))) unsigned int*)g,
      (__attribute__((address_space(3))) unsigned int*)l, 16, 0, 0);
}

__device__ __forceinline__ unsigned short f2bf(float f) {
  __hip_bfloat16 h = __float2bfloat16(f);
  return *reinterpret_cast<unsigned short*>(&h);
}

// ---------------------------------------------------------------------------
// Bt[o][r] = B[r][o]
// ---------------------------------------------------------------------------
__global__ __launch_bounds__(256) void transpose_B_k(const float* __restrict__ B,
                                                     float* __restrict__ Bt,
                                                     int Dout) {
  int idx = blockIdx.x * 256 + threadIdx.x;
  int r = idx / Dout;
  int o = idx - r * Dout;
  Bt[(long long)o * RANK + r] = B[idx];
}

// ---------------------------------------------------------------------------
// W' = W + SCALE*(A@B)^T, bf16, PRE-FRAGMENTED for mfma_32x32x16 B-operand:
//   frag (nb = o>>5, kb = i>>4) is a contiguous 1KB block; lane l holds 16B
//   = B'[k = (l>>5)*8 + e][col = l&31]  ->  l = ((i>>3)&1)*32 + (o&31), e=i&7
// ---------------------------------------------------------------------------
__global__ __launch_bounds__(256) void merge_W_k(const float* __restrict__ W,
                                                 const float* __restrict__ A,
                                                 const float* __restrict__ Bt,
                                                 unsigned short* __restrict__ Wbf,
                                                 int Din, int Dout) {
  __shared__ float sB[16 * RANK];
  int nib = Din / 256;
  int ib = blockIdx.x % nib;
  int ob = blockIdx.x / nib;
  int i0 = ib * 256, o0 = ob * 16;
  int t = threadIdx.x;

  if (t < 128) {
    reinterpret_cast<float4*>(sB)[t] =
        reinterpret_cast<const float4*>(Bt + (long long)o0 * RANK)[t];
  }

  float a[RANK];
  const float4* Ap = reinterpret_cast<const float4*>(A + (long long)(i0 + t) * RANK);
#pragma unroll
  for (int c = 0; c < RANK / 4; ++c) {
    float4 v = Ap[c];
    a[c * 4 + 0] = v.x; a[c * 4 + 1] = v.y;
    a[c * 4 + 2] = v.z; a[c * 4 + 3] = v.w;
  }
  __syncthreads();

  int i = i0 + t;
  int KB16 = Din >> 4;
  int kb = i >> 4;
  int lhalf = ((i >> 3) & 1) * 32;
  int e = i & 7;

  for (int o = 0; o < 16; ++o) {
    float d = 0.f;
#pragma unroll
    for (int j = 0; j < RANK; ++j) d += a[j] * sB[o * RANK + j];
    int oo = o0 + o;
    long long off = (long long)oo * Din + i;
    float w = __builtin_nontemporal_load(&W[off]);
    long long dst = (((long long)(oo >> 5) * KB16 + kb) * 64 + (lhalf + (oo & 31))) * 8 + e;
    Wbf[dst] = f2bf(w + SCALE * d);
  }
}

// ---------------------------------------------------------------------------
// x fp32 -> bf16, 8 elems/thread (nt loads via native ext_vector)
// ---------------------------------------------------------------------------
__global__ __launch_bounds__(256) void cast_x_k(const float* __restrict__ in,
                                                unsigned short* __restrict__ out,
                                                long long n8) {
  long long i = (long long)blockIdx.x * 256 + threadIdx.x;
  if (i >= n8) return;
  const f32x4* in4 = reinterpret_cast<const f32x4*>(in) + i * 2;
  f32x4 v0 = __builtin_nontemporal_load(in4);
  f32x4 v1 = __builtin_nontemporal_load(in4 + 1);
  union { unsigned short u[8]; uint4 q; } p;
  p.u[0] = f2bf(v0.x); p.u[1] = f2bf(v0.y); p.u[2] = f2bf(v0.z); p.u[3] = f2bf(v0.w);
  p.u[4] = f2bf(v1.x); p.u[5] = f2bf(v1.y); p.u[6] = f2bf(v1.z); p.u[7] = f2bf(v1.w);
  reinterpret_cast<uint4*>(out)[i] = p.q;
}

// ---------------------------------------------------------------------------
// R11: R10 schedule (proven ledger) with mfma_f32_32x32x16_bf16.
// 256x256 / BK=32 / 8 waves (2Mx4N) / A-only LDS 32KB dbuf / B direct from
// global (fragged Wbf, L2-hot).  MFMA floor 1241->1033 cyc/tile (m119),
// 8 MFMA/phase/wave instead of 16.
//
// Wave wr owns M rows {wr64+0..63} u {128+wr64+0..63} as 32-blocks
// mq: 0=wr64, 1=wr64+32, 2=128+wr64, 3=128+wr64+32; wc owns 64 cols
// (2x 32-blocks).  A-operand: lane&31 = row, k = (lane>>5)*8+e (symmetric to
// verified C/D map).  Per phase: 4 ds_read_b128 (bank-balanced under the
// existing swizzle - checked: all 32 banks exactly 8 accesses/read).
//
// Units & gates: identical to R10 (stages Ra1/Ra2, Bv group of 4):
//   PH1(X): gate vmcnt(1); stage Ra2(X+1); LOADB Bv(X+1); read aH(X); 8 MFMA lo
//   PH2(X): gate vmcnt(5); stage Ra1(X+2); read aL(X+1); 8 MFMA hi
//   Tail gates 1 -> 5 -> 0 (as R10).
// ---------------------------------------------------------------------------
__device__ __forceinline__ void stage1(const unsigned short* g, int K, int koff,
                                       int row0, unsigned short* ldsbase,
                                       int t, int wid) {
  int r = t >> 2;                               // 0..127 local row
  int cg = (t & 3) ^ ((r ^ (r >> 2)) & 3);      // inverse-swizzled 16B chunk
  gload16(g + (long long)(row0 + r) * K + koff + cg * 8,
          ldsbase + row0 * 32 + wid * 512);
}

__device__ __forceinline__ int swz_off32(int rowl, int k) {
  return rowl * 32 + ((((k) >> 3) ^ ((rowl ^ (rowl >> 2)) & 3)) << 3);
}

__global__ __launch_bounds__(512, 2) void gemm256_bias_k(
    const unsigned short* __restrict__ Xb,    // [M][K] bf16
    const unsigned short* __restrict__ Wbf,   // fragged [N/32][K/16][64][8]
    const float* __restrict__ bias,           // [N]
    float* __restrict__ Out,                  // [M][N] fp32
    int M, int N, int K) {
  __shared__ unsigned short As[2][256 * 32];  // 32 KiB

  int nbn = N / 256;
  int cpx = gridDim.x >> 3;
  int bid = blockIdx.x;
  int xcd = bid & 7, local = bid >> 3;
  int bm, bn;
  int mrows = cpx / nbn;
  if (mrows * nbn == cpx) {
    bn = local / mrows;
    bm = xcd * mrows + (local - bn * mrows);   // bm-fastest: B-panel L2-hot
  } else {
    int swz = xcd * cpx + local;
    bm = swz / nbn; bn = swz % nbn;
  }

  int t = threadIdx.x;
  int wid = t >> 6, lane = t & 63;
  int wr = wid >> 2, wc = wid & 3;             // 2x4 wave grid
  int lr32 = lane & 31, kq32 = (lane >> 5) * 8;
  int wr64 = wr * 64;

  const unsigned short* ga = Xb + (long long)bm * 256 * K;
  const int KB16 = K >> 4;                      // 256
  // B frag base: nb0 = bn*8 + wc*2; frags (nb0+n, 2T+kh)
  const unsigned short* gbf = Wbf + ((long long)(bn * 8 + wc * 2) * KB16) * 512
                                  + lane * 8;

  f32x16 acc[4][2] = {};
  bf16x8 aL0[2][2], aL1[2][2], aH0[2][2], aH1[2][2], Bv0[4], Bv1[4];

#define LDA32(BUF, ROWBASE, KH) \
  (*(const bf16x8*)&As[BUF][swz_off32((ROWBASE) + lr32, (KH) * 16 + kq32)])

#define GATE(NSTR) \
  asm volatile("s_waitcnt vmcnt(" NSTR ")" ::: "memory"); \
  __builtin_amdgcn_s_barrier();

#define READ_AH(AH, BUF) \
  AH[0][0] = LDA32(BUF, 128 + wr64, 0);      AH[0][1] = LDA32(BUF, 128 + wr64, 1); \
  AH[1][0] = LDA32(BUF, 128 + wr64 + 32, 0); AH[1][1] = LDA32(BUF, 128 + wr64 + 32, 1);

#define READ_AL(AL, BUF) \
  AL[0][0] = LDA32(BUF, wr64, 0);      AL[0][1] = LDA32(BUF, wr64, 1); \
  AL[1][0] = LDA32(BUF, wr64 + 32, 0); AL[1][1] = LDA32(BUF, wr64 + 32, 1);

#define LOADB(BV, T) { \
  const unsigned short* fb = gbf + (long long)(T) * 1024;              \
  BV[0] = *(const bf16x8*)(fb);                                        \
  BV[1] = *(const bf16x8*)(fb + 512);                                  \
  BV[2] = *(const bf16x8*)(fb + (long long)KB16 * 512);                \
  BV[3] = *(const bf16x8*)(fb + (long long)KB16 * 512 + 512); }

#define MFMA8(AF, BF, MO)                                                    \
  __builtin_amdgcn_sched_barrier(0);                                         \
  __builtin_amdgcn_s_setprio(1);                                             \
  _Pragma("unroll")                                                          \
  for (int mb = 0; mb < 2; ++mb)                                             \
    _Pragma("unroll")                                                        \
    for (int n = 0; n < 2; ++n) {                                            \
      acc[(MO) + mb][n] = __builtin_amdgcn_mfma_f32_32x32x16_bf16(           \
          AF[mb][0], BF[n * 2], acc[(MO) + mb][n], 0, 0, 0);                 \
      acc[(MO) + mb][n] = __builtin_amdgcn_mfma_f32_32x32x16_bf16(           \
          AF[mb][1], BF[n * 2 + 1], acc[(MO) + mb][n], 0, 0, 0);             \
    }                                                                        \
  __builtin_amdgcn_s_setprio(0);

  // ---- prologue: Ra1(0), Ra2(0), Bv(0), Ra1(1); vmcnt(1) leaves Ra1(1)
  stage1(ga, K, 0, 0,    &As[0][0], t, wid);   // Ra1(0)
  stage1(ga, K, 0, 128,  &As[0][0], t, wid);   // Ra2(0)
  LOADB(Bv0, 0)                                 // Bv(0) [4]
  stage1(ga, K, 32, 0,   &As[1][0], t, wid);   // Ra1(1)
  asm volatile("s_waitcnt vmcnt(1)" ::: "memory");
  __builtin_amdgcn_s_barrier();
  READ_AL(aL0, 0)

  // ---- steady loop: j covers X=2j (As[0]) and X=2j+1 (As[1]); j=0..62
  for (int j = 0; j < 63; ++j) {
    int ko = j * 64;  // 2j*32
    // PH1(X=2j): stage Ra2(X+1); load Bv(X+1); read aH(X); MFMA lo
    GATE("1")
    stage1(ga, K, ko + 32, 128, &As[1][0], t, wid);
    LOADB(Bv1, 2 * j + 1)
    READ_AH(aH0, 0)
    MFMA8(aL0, Bv0, 0)
    // PH2(X=2j): stage Ra1(X+2); read aL(X+1); MFMA hi
    GATE("5")
    stage1(ga, K, ko + 64, 0, &As[0][0], t, wid);
    READ_AL(aL1, 1)
    MFMA8(aH0, Bv0, 2)
    // PH1(X=2j+1): stage Ra2(X+2); load Bv(X+2); read aH(X+1); MFMA lo
    GATE("1")
    stage1(ga, K, ko + 64, 128, &As[0][0], t, wid);
    LOADB(Bv0, 2 * j + 2)
    READ_AH(aH1, 1)
    MFMA8(aL1, Bv1, 0)
    // PH2(X=2j+1): stage Ra1(X+3); read aL(X+2); MFMA hi
    GATE("5")
    stage1(ga, K, ko + 96, 0, &As[1][0], t, wid);
    READ_AL(aL0, 0)
    MFMA8(aH1, Bv1, 2)
  }

  // ---- peeled tail: X=126 (As[0]), X=127 (As[1])
  GATE("1")
  stage1(ga, K, 127 * 32, 128, &As[1][0], t, wid);   // Ra2(127)
  LOADB(Bv1, 127)
  READ_AH(aH0, 0)
  MFMA8(aL0, Bv0, 0)
  GATE("5")
  READ_AL(aL1, 1)
  MFMA8(aH0, Bv0, 2)
  GATE("0")
  READ_AH(aH1, 1)
  MFMA8(aL1, Bv1, 0)
  MFMA8(aH1, Bv1, 2)

#undef LDA32
#undef GATE
#undef READ_AH
#undef READ_AL
#undef LOADB
#undef MFMA8

  // epilogue (nt stores), 32x32 C/D map (m74/m101): col=lane&31,
  // row = (r&3) + 8*(r>>2) + 4*(lane>>5)
  int rq5 = 4 * (lane >> 5);
#pragma unroll
  for (int mq = 0; mq < 4; ++mq) {
    long long grb = (long long)bm * 256 + (mq >= 2 ? 128 : 0) + wr64 + (mq & 1) * 32 + rq5;
#pragma unroll
    for (int n = 0; n < 2; ++n) {
      int gc = bn * 256 + wc * 64 + n * 32 + lr32;
      float bv = bias[gc];
#pragma unroll
      for (int r = 0; r < 16; ++r) {
        long long gr = grb + (r & 3) + 8 * (r >> 2);
        __builtin_nontemporal_store(acc[mq][n][r] + bv, &Out[gr * N + gc]);
      }
    }
  }
}

// ---------------------------------------------------------------------------
extern "C" void kernel_launch(void* const* d_in, const int* in_sizes, int n_in,
                              void* d_out, int out_size, void* d_ws, size_t ws_size,
                              hipStream_t stream) {
  const float* x    = (const float*)d_in[0];
  const float* W    = (const float*)d_in[1];
  const float* bias = (const float*)d_in[2];
  const float* A    = (const float*)d_in[3];
  const float* B    = (const float*)d_in[4];

  int Din  = in_sizes[3] / RANK;                 // 4096
  int Dout = in_sizes[4] / RANK;                 // 4096
  long long M = (long long)in_sizes[0] / Din;    // 8192

  size_t xb_bytes = (size_t)M * Din * 2;
  size_t wb_bytes = (size_t)Dout * Din * 2;
  size_t bt_bytes = (size_t)Dout * RANK * 4;
  if (ws_size < xb_bytes + wb_bytes + bt_bytes) return;

  char* ws = (char*)d_ws;
  unsigned short* Xb  = (unsigned short*)ws;
  unsigned short* Wbf = (unsigned short*)(ws + xb_bytes);
  float* Bt           = (float*)(ws + xb_bytes + wb_bytes);

  transpose_B_k<<<dim3((Dout * RANK) / 256), dim3(256), 0, stream>>>(B, Bt, Dout);
  merge_W_k<<<dim3((Dout / 16) * (Din / 256)), dim3(256), 0, stream>>>(W, A, Bt, Wbf, Din, Dout);
  long long n8 = M * Din / 8;
  cast_x_k<<<dim3((unsigned)(n8 / 256)), dim3(256), 0, stream>>>(x, Xb, n8);
  gemm256_bias_k<<<dim3((unsigned)((M / 256) * (Dout / 256))), dim3(512), 0, stream>>>(
      Xb, Wbf, bias, (float*)d_out, (int)M, Dout, Din);
}